// Round 5
// baseline (29.152 us; speedup 1.0000x reference)
//
#include <hip/hip_runtime.h>

// Shapes fixed by reference setup_inputs(): (B=16, NI=11, T=65536), LST=64.
#define B_   16
#define NI   11
#define T_   65536
#define LST  64
#define ROW2 132            // LDS row stride (floats): 528B, 16B-aligned

#define DPP_XOR1 0xB1       // quad_perm(1,0,3,2)  == xor lane^1
#define DPP_XOR2 0x4E       // quad_perm(2,3,0,1)  == xor lane^2

__device__ __forceinline__ float frcp(float x) { return __builtin_amdgcn_rcpf(x); }

template<int CTRL>
__device__ __forceinline__ float dppf(float x) {
    return __int_as_float(__builtin_amdgcn_update_dpp(
        0, __float_as_int(x), CTRL, 0xF, 0xF, true));
}

// One wave per SUPER-tile: 11 instruments x 128 timesteps (2 LST blocks).
// Fully fused, read once / write once. Sparsemax taus via max-init Michelot
// (tau* >= max-1; threshold-set iteration; count-stable stop == exact KKT).
// All cross-lane reduction is quad-local -> DPP on the VALU pipe (no DS).
__global__ __launch_bounds__(256, 6) void fused_sparsemax_kernel(
        const float* __restrict__ in, float* __restrict__ out) {
    __shared__ float ldsz[4][NI * ROW2];   // z super-tile [inst][128+pad]
    __shared__ float ldsti[4][128];        // tau_inst[t] transpose buffer

    const int lane = threadIdx.x & 63;
    const int wid  = threadIdx.x >> 6;
    const int st   = blockIdx.x * 4 + wid;       // 8192 super-tiles
    const int b    = st >> 9;                    // 512 super-tiles per batch
    const int j2   = st & 511;

    const float* px = in + (size_t)b * NI * T_ + (size_t)j2 * 128
                         + (size_t)lane * 2;

    // ---- load: 11 coalesced dwordx2 loads (one per instrument row) ----
    float2 z[NI];
#pragma unroll
    for (int i = 0; i < NI; ++i)
        z[i] = *reinterpret_cast<const float2*>(px + (size_t)i * T_);

    // stage to LDS early (b64 writes, conflict-free)
#pragma unroll
    for (int i = 0; i < NI; ++i)
        *reinterpret_cast<float2*>(&ldsz[wid][i * ROW2 + lane * 2]) = z[i];

    // ---- instrument tau: 2 interleaved per-lane Michelot chains (d=11) ----
    float mxa = z[0].x, mxb = z[0].y;
#pragma unroll
    for (int i = 1; i < NI; ++i) {
        mxa = fmaxf(mxa, z[i].x);
        mxb = fmaxf(mxb, z[i].y);
    }
    float ta = mxa - 1.0f, tb = mxb - 1.0f;
    float pa = 0.0f, pb = 0.0f;
    for (int it = 0; it < NI + 2; ++it) {
        float sa = 0.0f, ca = 0.0f, sb = 0.0f, cb = 0.0f;
#pragma unroll
        for (int i = 0; i < NI; ++i) {
            bool aa = z[i].x > ta;
            sa += aa ? z[i].x : 0.0f;
            ca += aa ? 1.0f : 0.0f;
            bool ab = z[i].y > tb;
            sb += ab ? z[i].y : 0.0f;
            cb += ab ? 1.0f : 0.0f;
        }
        bool changed = (ca != pa) || (cb != pb);
        if (!__any(changed)) break;        // stable threshold-set -> exact
        pa = ca; pb = cb;
        ta = (sa - 1.0f) * frcp(ca);
        tb = (sb - 1.0f) * frcp(cb);
    }
    *reinterpret_cast<float2*>(&ldsti[wid][lane * 2]) = make_float2(ta, tb);

    // ---- time tau + epilogue, per LST block; 4-lane group g = inst row ----
    const int g   = lane >> 2;
    const int q   = lane & 3;
    const int row = (g < NI) ? g : (g - NI);     // spare groups duplicate

#pragma unroll
    for (int tile = 0; tile < 2; ++tile) {
        const int cb = tile * 64 + q * 16;

        float y[16];                              // 4x ds_read_b128
#pragma unroll
        for (int r = 0; r < 16; ++r) y[r] = ldsz[wid][row * ROW2 + cb + r];

        float m = y[0];
#pragma unroll
        for (int r = 1; r < 16; ++r) m = fmaxf(m, y[r]);
        m = fmaxf(m, dppf<DPP_XOR1>(m));
        m = fmaxf(m, dppf<DPP_XOR2>(m));

        float tau = m - 1.0f, prev = 0.0f;
        for (int it = 0; it < LST + 2; ++it) {
            float sp = 0.0f, cp = 0.0f;
#pragma unroll
            for (int r = 0; r < 16; ++r) {
                bool a = y[r] > tau;
                sp += a ? y[r] : 0.0f;
                cp += a ? 1.0f : 0.0f;
            }
            sp += dppf<DPP_XOR1>(sp);
            sp += dppf<DPP_XOR2>(sp);
            cp += dppf<DPP_XOR1>(cp);
            cp += dppf<DPP_XOR2>(cp);
            bool changed = (cp != prev);
            if (!__any(changed)) break;           // all groups stable
            prev = cp;
            tau = (sp - 1.0f) * frcp(cp);
        }

        if (g < NI) {
            float ti[16];                         // 4x ds_read_b128, broadcast
#pragma unroll
            for (int r = 0; r < 16; ++r) ti[r] = ldsti[wid][cb + r];

            float* po = out + (size_t)b * NI * T_ + (size_t)g * T_
                            + (size_t)j2 * 128 + cb;
            float4* po4 = reinterpret_cast<float4*>(po);
#pragma unroll
            for (int v = 0; v < 4; ++v) {
                float4 o;
                o.x = fmaxf(y[4*v+0] - tau, 0.0f) * fmaxf(y[4*v+0] - ti[4*v+0], 0.0f);
                o.y = fmaxf(y[4*v+1] - tau, 0.0f) * fmaxf(y[4*v+1] - ti[4*v+1], 0.0f);
                o.z = fmaxf(y[4*v+2] - tau, 0.0f) * fmaxf(y[4*v+2] - ti[4*v+2], 0.0f);
                o.w = fmaxf(y[4*v+3] - tau, 0.0f) * fmaxf(y[4*v+3] - ti[4*v+3], 0.0f);
                po4[v] = o;
            }
        }
    }
}

extern "C" void kernel_launch(void* const* d_in, const int* in_sizes, int n_in,
                              void* d_out, int out_size, void* d_ws, size_t ws_size,
                              hipStream_t stream) {
    const float* in = (const float*)d_in[0];
    float* out = (float*)d_out;
    // 8192 super-tiles, 4 waves per 256-thread block -> 2048 blocks
    hipLaunchKernelGGL(fused_sparsemax_kernel, dim3(2048), dim3(256), 0, stream,
                       in, out);
}

// Round 6
// 28.512 us; speedup vs baseline: 1.0224x; 1.0224x over previous
//
#include <hip/hip_runtime.h>

// Shapes fixed by reference setup_inputs(): (B=16, NI=11, T=65536), LST=64.
#define B_   16
#define NI   11
#define T_   65536
#define LST  64
#define NBLK (T_ / LST)     // 1024
#define ROWP 68             // LDS row stride (floats): 272B, 16B-aligned

#define DPP_XOR1 0xB1       // quad_perm(1,0,3,2)  == xor lane^1
#define DPP_XOR2 0x4E       // quad_perm(2,3,0,1)  == xor lane^2

__device__ __forceinline__ float frcp(float x) { return __builtin_amdgcn_rcpf(x); }

template<int CTRL>
__device__ __forceinline__ float dppf(float x) {
    return __int_as_float(__builtin_amdgcn_update_dpp(
        0, __float_as_int(x), CTRL, 0xF, 0xF, true));
}
template<int CTRL>
__device__ __forceinline__ int dppi(int x) {
    return __builtin_amdgcn_update_dpp(0, x, CTRL, 0xF, 0xF, true);
}

// One wave per (b, jb) tile of 11 instruments x 64 timesteps. Fully fused,
// read once / write once. Max-init Michelot for both taus (tau0 = max-1 is
// always a lower bound whose support is a superset of the true support;
// support shrinks monotonically; count-stable stop == exact KKT point).
// Inner loop: one v_cmp shared by float-sum (cndmask+add) and int-count
// (addc from vcc) = 4 VALU/elem. Quad reduces are single-instr DPP.
__global__ __launch_bounds__(256) void fused_sparsemax_kernel(
        const float* __restrict__ in, float* __restrict__ out) {
    __shared__ float ldsz[4][NI * ROWP];   // z tile, row-major [inst][t]
    __shared__ float ldsti[4][64];         // tau_inst[t] transpose buffer

    const int lane = threadIdx.x & 63;
    const int wid  = threadIdx.x >> 6;
    const int tile = blockIdx.x * 4 + wid;          // 16384 tiles
    const int b    = tile >> 10;
    const int jb   = tile & (NBLK - 1);

    const float* px = in + (size_t)b * NI * T_ + (size_t)jb * LST + (size_t)lane;

    // ---- load: 11 coalesced 4B loads (one per instrument row) ----
    float z[NI];
#pragma unroll
    for (int i = 0; i < NI; ++i) z[i] = px[(size_t)i * T_];

    // stage tile to LDS early (latency hides under tau_inst compute)
#pragma unroll
    for (int i = 0; i < NI; ++i) ldsz[wid][i * ROWP + lane] = z[i];

    // ---- instrument tau: per-lane max-init Michelot over d=11 ----
    float mx = z[0];
#pragma unroll
    for (int i = 1; i < NI; ++i) mx = fmaxf(mx, z[i]);
    float tau_i = mx - 1.0f;
    int prevc = 0;
    for (int it = 0; it < NI + 1; ++it) {            // <=10 shrinks + 1 detect
        float s = 0.0f;
        int   c = 0;
#pragma unroll
        for (int i = 0; i < NI; ++i) {
            bool a = z[i] > tau_i;
            s += a ? z[i] : 0.0f;
            c += a ? 1 : 0;
        }
        if (!__any(c != prevc)) break;               // support stable -> exact
        prevc = c;
        tau_i = (s - 1.0f) * frcp((float)c);
    }
    ldsti[wid][lane] = tau_i;                        // lane == t within block

    // ---- time tau: 4-lane group g owns instrument row g (g<11) ----
    const int g   = lane >> 2;
    const int q   = lane & 3;
    const int row = (g < NI) ? g : (g - NI);         // spare groups duplicate

    float y[16];                                     // 4x ds_read_b128
#pragma unroll
    for (int r = 0; r < 16; ++r) y[r] = ldsz[wid][row * ROWP + q * 16 + r];

    float m = y[0];
#pragma unroll
    for (int r = 1; r < 16; ++r) m = fmaxf(m, y[r]);
    m = fmaxf(m, dppf<DPP_XOR1>(m));
    m = fmaxf(m, dppf<DPP_XOR2>(m));

    float tau = m - 1.0f;
    int prev = 0;
    for (int it = 0; it < LST + 1; ++it) {           // <=63 shrinks + 1 detect
        float s = 0.0f;
        int   c = 0;
#pragma unroll
        for (int r = 0; r < 16; ++r) {
            bool a = y[r] > tau;
            s += a ? y[r] : 0.0f;
            c += a ? 1 : 0;
        }
        s += dppf<DPP_XOR1>(s);
        s += dppf<DPP_XOR2>(s);
        c += dppi<DPP_XOR1>(c);
        c += dppi<DPP_XOR2>(c);
        if (!__any(c != prev)) break;                // all groups stable
        prev = c;
        tau = (s - 1.0f) * frcp((float)c);
    }

    // ---- epilogue in group layout: float4 stores, tau_inst via LDS ----
    if (g < NI) {
        float ti[16];                                // 4x ds_read_b128
#pragma unroll
        for (int r = 0; r < 16; ++r) ti[r] = ldsti[wid][q * 16 + r];

        float* po = out + (size_t)b * NI * T_ + (size_t)g * T_
                        + (size_t)jb * LST + (size_t)q * 16;
        float4* po4 = reinterpret_cast<float4*>(po);
#pragma unroll
        for (int v = 0; v < 4; ++v) {
            float4 o;
            o.x = fmaxf(y[4*v+0] - tau, 0.0f) * fmaxf(y[4*v+0] - ti[4*v+0], 0.0f);
            o.y = fmaxf(y[4*v+1] - tau, 0.0f) * fmaxf(y[4*v+1] - ti[4*v+1], 0.0f);
            o.z = fmaxf(y[4*v+2] - tau, 0.0f) * fmaxf(y[4*v+2] - ti[4*v+2], 0.0f);
            o.w = fmaxf(y[4*v+3] - tau, 0.0f) * fmaxf(y[4*v+3] - ti[4*v+3], 0.0f);
            po4[v] = o;
        }
    }
}

extern "C" void kernel_launch(void* const* d_in, const int* in_sizes, int n_in,
                              void* d_out, int out_size, void* d_ws, size_t ws_size,
                              hipStream_t stream) {
    const float* in = (const float*)d_in[0];
    float* out = (float*)d_out;
    // 16384 wave-tiles, 4 waves per 256-thread block -> 4096 blocks
    hipLaunchKernelGGL(fused_sparsemax_kernel, dim3(4096), dim3(256), 0, stream,
                       in, out);
}